// Round 12
// baseline (67.165 us; speedup 1.0000x reference)
//
#include <hip/hip_runtime.h>
#include <hip/hip_bf16.h>

#define BATCH 32768
#define NPAIR 64
#define NBLK  128

typedef __bf16 bf16x8 __attribute__((ext_vector_type(8)));
typedef float  f32x4  __attribute__((ext_vector_type(4)));
static_assert(sizeof(bf16x8) == 16, "bf16x8 must be 16B");

// ---- workspace byte offsets ----
#define WS_CNT      0
#define WS_BASE     256        /* padded (32-aligned) pair bases */
#define WS_BH       1024
#define WS_PAIR     66560
#define WS_ROWLIST  197632     /* padded, 34816 ints */
#define WS_WF00     336896     /* frag-major [m][NT16][KC2][64]x16B = 32KB/m */
#define WS_WF01     599040     /* [m][NT8][KC8][64] = 64KB/m */
#define WS_WF1P     1123328    /* 32KB/m */
#define WS_WF1A     1385472    /* [m][NT8][KC12][64] = 96KB/m */
#define WS_WF1O     2171904    /* [m][NT2][KC4][64] = 8KB/m */
#define WS_F2       2237440    /* frag-major [pos16<=2176][kcb4][64]x16B = 8.9MB */

__device__ __forceinline__ unsigned short f2bf(float x) {
  __bf16 h = (__bf16)x;
  return __builtin_bit_cast(unsigned short, h);
}

#define KEEP(x) asm volatile("" : "+v"(x))
#define PIN8(A) asm volatile("" :: \
  "v"((A)[0]),"v"((A)[1]),"v"((A)[2]),"v"((A)[3]), \
  "v"((A)[4]),"v"((A)[5]),"v"((A)[6]),"v"((A)[7]))

__device__ __forceinline__ bf16x8 gather_frag(const float* __restrict__ inp,
                                              int rg, int colofs, int kc, int kcol) {
  bf16x8 a;
  if (rg >= 0) {
    const float* q = inp + (size_t)rg * 144 + colofs + kc * 32 + kcol;
    float4 u = *(const float4*)(q);
    float4 v = *(const float4*)(q + 4);
    a[0] = (__bf16)u.x; a[1] = (__bf16)u.y; a[2] = (__bf16)u.z; a[3] = (__bf16)u.w;
    a[4] = (__bf16)v.x; a[5] = (__bf16)v.y; a[6] = (__bf16)v.z; a[7] = (__bf16)v.w;
  } else {
    #pragma unroll
    for (int j = 0; j < 8; ++j) a[j] = (__bf16)0.f;
  }
  return a;
}

// Blocks 0..239: weight fp32 -> bf16 MFMA-fragment-major. Blocks 240..367: route.
__global__ __launch_bounds__(256) void k_combo(const float* __restrict__ w00,
                                               const float* __restrict__ w01,
                                               const float* __restrict__ w1p,
                                               const float* __restrict__ w1a,
                                               const float* __restrict__ w1o,
                                               const float* __restrict__ inp,
                                               char* __restrict__ ws) {
  __shared__ unsigned short lds[64 * 72];
  int bid = blockIdx.x;
  if (bid >= 240) {
    int* h = (int*)lds;
    int rbid = bid - 240;
    int t = threadIdx.x;
    if (t < NPAIR) h[t] = 0;
    __syncthreads();
    int r = rbid * 256 + t;
    const float* q = inp + (size_t)r * 144 + 128;
    float4 u0 = *(const float4*)(q + 0);
    float4 u1 = *(const float4*)(q + 4);
    float4 v0 = *(const float4*)(q + 8);
    float4 v1 = *(const float4*)(q + 12);
    int a0 = 0;
    if (u0.y > 0.5f) a0 = 1; if (u0.z > 0.5f) a0 = 2; if (u0.w > 0.5f) a0 = 3;
    if (u1.x > 0.5f) a0 = 4; if (u1.y > 0.5f) a0 = 5; if (u1.z > 0.5f) a0 = 6; if (u1.w > 0.5f) a0 = 7;
    int a1 = 0;
    if (v0.y > 0.5f) a1 = 1; if (v0.z > 0.5f) a1 = 2; if (v0.w > 0.5f) a1 = 3;
    if (v1.x > 0.5f) a1 = 4; if (v1.y > 0.5f) a1 = 5; if (v1.z > 0.5f) a1 = 6; if (v1.w > 0.5f) a1 = 7;
    int p = a0 * 8 + a1;
    ((int*)(ws + WS_PAIR))[r] = p;
    atomicAdd(&h[p], 1);
    __syncthreads();
    if (t < NPAIR) ((int*)(ws + WS_BH))[rbid * NPAIR + t] = h[t];
    return;
  }
  const float* src; char* dst; int I, O, lt, NT, KC;
  if (bid < 32)       { src = w00; dst = ws + WS_WF00; I = 64;  O = 256; lt = bid;       NT = 16; KC = 2; }
  else if (bid < 96)  { src = w01; dst = ws + WS_WF01; I = 256; O = 128; lt = bid - 32;  NT = 8;  KC = 8; }
  else if (bid < 128) { src = w1p; dst = ws + WS_WF1P; I = 64;  O = 256; lt = bid - 96;  NT = 16; KC = 2; }
  else if (bid < 224) { src = w1a; dst = ws + WS_WF1A; I = 384; O = 128; lt = bid - 128; NT = 8;  KC = 12; }
  else                { src = w1o; dst = ws + WS_WF1O; I = 128; O = 32;  lt = bid - 224; NT = 2;  KC = 4; }
  int tI = I >> 6;
  int tO = (O + 63) >> 6;
  int m   = lt / (tI * tO);
  int rem = lt % (tI * tO);
  int ib = rem / tO, ob = rem % tO;
  int tx = threadIdx.x & 63, ty = threadIdx.x >> 6;
  const float* s = src + (size_t)m * I * O;
  #pragma unroll 4
  for (int s4 = 0; s4 < 16; ++s4) {
    int li = s4 * 4 + ty;
    int o  = ob * 64 + tx;
    float v = (o < O) ? s[(size_t)(ib * 64 + li) * O + o] : 0.f;
    lds[li * 72 + tx] = f2bf(v);
  }
  __syncthreads();
  int lane = threadIdx.x & 63, u = threadIdx.x >> 6;
  int ln = lane & 15, lq = lane >> 4;
  #pragma unroll
  for (int it = 0; it < 2; ++it) {
    int fi  = it * 4 + u;
    int ntl = fi >> 1, kcl = fi & 1;
    int ntg = ob * 4 + ntl, kcg = ib * 2 + kcl;
    if (ntg * 16 < O) {
      bf16x8 f;
      #pragma unroll
      for (int j = 0; j < 8; ++j)
        f[j] = __builtin_bit_cast(__bf16, lds[(kcl * 32 + lq * 8 + j) * 72 + ntl * 16 + ln]);
      *(bf16x8*)(dst + (((size_t)(m * NT + ntg) * KC + kcg) * 64 + lane) * 16) = f;
    }
  }
}

// k_part: scan (redundant per block, from bh in LDS) + scatter in ONE kernel.
__global__ __launch_bounds__(256) void k_part(const int* __restrict__ bh,
                                              const int* __restrict__ pairArr,
                                              int* __restrict__ cnt,
                                              int* __restrict__ base,
                                              int* __restrict__ rowlist) {
  __shared__ int lbh[NBLK * NPAIR];   // 32KB
  __shared__ int loff[NPAIR];
  __shared__ int h[NPAIR];
  int tid = threadIdx.x, bid = blockIdx.x;
  const int4* s4 = (const int4*)bh;
  int4* d4 = (int4*)lbh;
  #pragma unroll
  for (int i = 0; i < 8; ++i) d4[tid + i * 256] = s4[tid + i * 256];
  if (tid < NPAIR) h[tid] = 0;
  __syncthreads();
  if (tid < NPAIR) {
    int c = 0, partial = 0;
    for (int b = 0; b < NBLK; ++b) {
      int v = lbh[b * NPAIR + tid];
      if (b < bid) partial += v;
      c += v;
    }
    int ntp = (c + 31) >> 5;
    int z = ntp;
    #pragma unroll
    for (int d = 1; d < 64; d <<= 1) { int y = __shfl_up(z, d); if (tid >= d) z += y; }
    int pbase = (z - ntp) * 32;
    loff[tid] = pbase + partial;
    if (bid == 0) { cnt[tid] = c; base[tid] = pbase; }
  }
  __syncthreads();
  int r = bid * 256 + tid;
  int p = pairArr[r];
  int rank = atomicAdd(&h[p], 1);
  rowlist[loff[p] + rank] = r;
}

// Kernel A: e0-branch. LDS 80K -> 2 blocks/CU. WF01 64K @0, H1 16K @65536
// (FS tile-stage aliases H1). F2 emitted FRAG-MAJOR via LDS re-stage:
// one contiguous 1024B store per wave (full lines, no partial-line RMW).
__global__ __launch_bounds__(512, 4) void k_fwdA(
    const float* __restrict__ inp,
    const float* __restrict__ b00, const float* __restrict__ b01,
    char* __restrict__ ws)
{
  __shared__ char smem[81920];
  unsigned short* H1m = (unsigned short*)(smem + 65536);
  unsigned short* FS  = (unsigned short*)(smem + 65536);  // aliases H1 (barrier-guarded)

  int p     = blockIdx.x >> 3;
  int slice = blockIdx.x & 7;
  int e0 = p >> 3;
  int cnt = ((const int*)(ws + WS_CNT))[p];
  int pbase = ((const int*)(ws + WS_BASE))[p];
  int ntp = (cnt + 31) >> 5;
  if (slice >= ntp) return;
  const int* rlbase = (const int*)(ws + WS_ROWLIST) + pbase;
  char* f2 = ws + WS_F2;

  int tid = threadIdx.x;
  {
    const float4* s1 = (const float4*)(ws + WS_WF01 + (size_t)e0 * 65536);
    float4* d1 = (float4*)smem;
    #pragma unroll
    for (int i = 0; i < 8; ++i) d1[tid + i * 512] = s1[tid + i * 512];
  }

  int lane = tid & 63;
  int w    = tid >> 6;
  int ln = lane & 15, lq = lane >> 4, kcol = lq * 8;

  bf16x8 w00f[2][2];
  #pragma unroll
  for (int nt = 0; nt < 2; ++nt)
    #pragma unroll
    for (int kc = 0; kc < 2; ++kc)
      w00f[nt][kc] = *(const bf16x8*)(ws + WS_WF00 + (size_t)e0 * 32768 +
                                      ((((w * 2 + nt) * 2 + kc) * 64 + lane) << 4));
  #pragma unroll
  for (int nt = 0; nt < 2; ++nt)
    #pragma unroll
    for (int kc = 0; kc < 2; ++kc) KEEP(w00f[nt][kc]);

  float bias00[2];
  #pragma unroll
  for (int nt = 0; nt < 2; ++nt) bias00[nt] = b00[e0 * 256 + w * 32 + nt * 16 + ln];
  float bias01 = b01[e0 * 128 + w * 16 + ln];

  const f32x4 z4 = {0.f, 0.f, 0.f, 0.f};
  __syncthreads();  // weights staged

  for (int t = slice; t < ntp; t += 8) {
    int nr = min(32, cnt - t * 32);
    int rb = pbase + t * 32;
    const int* rl = rlbase + t * 32;

    int rowA[2];
    #pragma unroll
    for (int mt = 0; mt < 2; ++mt) {
      int rloc = mt * 16 + ln;
      rowA[mt] = (rloc < nr) ? rl[rloc] : -1;
    }
    bf16x8 axf[2][2];
    #pragma unroll
    for (int mt = 0; mt < 2; ++mt)
      #pragma unroll
      for (int kc = 0; kc < 2; ++kc)
        axf[mt][kc] = gather_frag(inp, rowA[mt], 0, kc, kcol);

    // P1: L00 (reg weights) -> H1 (swizzled)
    #pragma unroll
    for (int nt = 0; nt < 2; ++nt) {
      int n = w * 32 + nt * 16 + ln;
      f32x4 acc[2] = {z4, z4};
      #pragma unroll
      for (int kc = 0; kc < 2; ++kc)
        #pragma unroll
        for (int mt = 0; mt < 2; ++mt)
          acc[mt] = __builtin_amdgcn_mfma_f32_16x16x32_bf16(axf[mt][kc], w00f[nt][kc], acc[mt], 0, 0, 0);
      #pragma unroll
      for (int mt = 0; mt < 2; ++mt)
        #pragma unroll
        for (int r = 0; r < 4; ++r) {
          int row = mt * 16 + lq * 4 + r;
          float v = fmaxf(acc[mt][r] + bias00[nt], 0.f);
          H1m[(row * 512 + ((n << 1) ^ ((row & 7) << 4))) >> 1] = f2bf(v);
        }
    }
    __syncthreads();  // bar1: H1 ready

    // P2: L01 (LDS weights) -> acc
    f32x4 acc[2] = {z4, z4};
    #pragma unroll
    for (int kc = 0; kc < 8; ++kc) {
      bf16x8 bfr = *(const bf16x8*)(smem + (((w * 8 + kc) * 64 + lane) << 4));
      #pragma unroll
      for (int mt = 0; mt < 2; ++mt) {
        int row = mt * 16 + ln;
        bf16x8 afr = *(const bf16x8*)&H1m[(row * 512 + (((kc * 32 + kcol) << 1) ^ ((row & 7) << 4))) >> 1];
        acc[mt] = __builtin_amdgcn_mfma_f32_16x16x32_bf16(afr, bfr, acc[mt], 0, 0, 0);
      }
    }
    __syncthreads();  // bar2: all H1 reads done -> FS may overwrite

    // FS = relu(acc+b01), swizzled 32x128 (stride 256B), aliases H1
    {
      int c = w * 16 + ln;
      #pragma unroll
      for (int mt = 0; mt < 2; ++mt)
        #pragma unroll
        for (int r = 0; r < 4; ++r) {
          int row = mt * 16 + lq * 4 + r;
          float v = fmaxf(acc[mt][r] + bias01, 0.f);
          FS[(row * 256 + ((c << 1) ^ ((row & 7) << 4))) >> 1] = f2bf(v);
        }
    }
    __syncthreads();  // bar3: FS ready

    // frag-major F2 store: wave w -> frag (mt=w>>2, kcb=w&3); 1024B contiguous
    {
      int mt = w >> 2, kcb = w & 3;
      int row = mt * 16 + ln;
      int koff = kcb * 32 + lq * 8;
      bf16x8 v = *(const bf16x8*)&FS[(row * 256 + ((koff << 1) ^ ((row & 7) << 4))) >> 1];
      *(bf16x8*)(f2 + ((size_t)(((rb >> 4) + mt) * 4 + kcb)) * 1024 + lane * 16) = v;
    }
    __syncthreads();  // bar4: FS reads done before next P1 rewrites H1
  }
}

// Kernel B: e1-branch. LDS 72K -> 2 blocks/CU. WF1A kc<6 (48K) @0,
// G 16K @49152, G2 8K @65536. WF1P / WF1A kc>=6 / WF1O in regs.
// F2 frag reads now lane-contiguous. 2 barriers per tile.
__global__ __launch_bounds__(512, 4) void k_fwdB(
    const float* __restrict__ inp,
    const float* __restrict__ b1p, const float* __restrict__ b1a,
    const float* __restrict__ b1o,
    char* __restrict__ ws, float* __restrict__ out)
{
  __shared__ char smem[73728];
  unsigned short* G  = (unsigned short*)(smem + 49152);
  unsigned short* G2 = (unsigned short*)(smem + 65536);

  int p     = blockIdx.x >> 3;
  int slice = blockIdx.x & 7;
  int e1 = p & 7;
  int cnt = ((const int*)(ws + WS_CNT))[p];
  int pbase = ((const int*)(ws + WS_BASE))[p];
  int ntp = (cnt + 31) >> 5;
  if (slice >= ntp) return;
  const int* rlbase = (const int*)(ws + WS_ROWLIST) + pbase;
  const char* f2 = ws + WS_F2;

  int tid = threadIdx.x;
  {
    const float4* s1 = (const float4*)(ws + WS_WF1A + (size_t)e1 * 98304);
    float4* d1 = (float4*)smem;
    #pragma unroll
    for (int i = 0; i < 6; ++i) {
      int fidx = tid + i * 512;
      int chunk = fidx >> 6, within = fidx & 63;
      int w2 = chunk / 6, kc = chunk % 6;
      d1[fidx] = s1[(w2 * 12 + kc) * 64 + within];
    }
  }

  int lane = tid & 63;
  int w    = tid >> 6;
  int ln = lane & 15, lq = lane >> 4, kcol = lq * 8;

  bf16x8 w1pf[2][2];
  #pragma unroll
  for (int nt = 0; nt < 2; ++nt)
    #pragma unroll
    for (int kc = 0; kc < 2; ++kc)
      w1pf[nt][kc] = *(const bf16x8*)(ws + WS_WF1P + (size_t)e1 * 32768 +
                                      ((((w * 2 + nt) * 2 + kc) * 64 + lane) << 4));
  bf16x8 wa_hi[6];
  #pragma unroll
  for (int j = 0; j < 6; ++j)
    wa_hi[j] = *(const bf16x8*)(ws + WS_WF1A + (size_t)e1 * 98304 +
                                (((w * 12 + 6 + j) * 64 + lane) << 4));
  bf16x8 wo[4];
  if (w < 4) {
    #pragma unroll
    for (int kc = 0; kc < 4; ++kc)
      wo[kc] = *(const bf16x8*)(ws + WS_WF1O + (size_t)e1 * 8192 +
                                ((((w >> 1) * 4 + kc) * 64 + lane) << 4));
  }
  #pragma unroll
  for (int nt = 0; nt < 2; ++nt)
    #pragma unroll
    for (int kc = 0; kc < 2; ++kc) KEEP(w1pf[nt][kc]);
  #pragma unroll
  for (int j = 0; j < 6; ++j) KEEP(wa_hi[j]);
  if (w < 4) {
    #pragma unroll
    for (int kc = 0; kc < 4; ++kc) KEEP(wo[kc]);
  }

  float bias1p[2];
  #pragma unroll
  for (int nt = 0; nt < 2; ++nt) bias1p[nt] = b1p[e1 * 256 + w * 32 + nt * 16 + ln];
  float bias1a = b1a[e1 * 128 + w * 16 + ln];
  float bias1o = (w < 4) ? b1o[e1 * 32 + (w >> 1) * 16 + ln] : 0.f;

  const f32x4 z4 = {0.f, 0.f, 0.f, 0.f};
  __syncthreads();  // weights staged

  for (int t = slice; t < ntp; t += 8) {
    int nr = min(32, cnt - t * 32);
    int rb = pbase + t * 32;
    const int* rl = rlbase + t * 32;

    int rowA[2];
    #pragma unroll
    for (int mt = 0; mt < 2; ++mt) {
      int rloc = mt * 16 + ln;
      rowA[mt] = (rloc < nr) ? rl[rloc] : -1;
    }
    bf16x8 axf[2][2];
    #pragma unroll
    for (int mt = 0; mt < 2; ++mt)
      #pragma unroll
      for (int kc = 0; kc < 2; ++kc)
        axf[mt][kc] = gather_frag(inp, rowA[mt], 64, kc, kcol);

    // prefetch F2 A-frags (frag-major, lane-contiguous 16B)
    bf16x8 ff[8];
    #pragma unroll
    for (int mt = 0; mt < 2; ++mt) {
      size_t pb = (size_t)(((rb >> 4) + mt) * 4) * 1024;
      #pragma unroll
      for (int kcb = 0; kcb < 4; ++kcb)
        ff[mt * 4 + kcb] = *(const bf16x8*)(f2 + pb + kcb * 1024 + lane * 16);
    }
    PIN8(ff);

    // P1: L1p (reg weights) -> G (swizzled)
    #pragma unroll
    for (int nt = 0; nt < 2; ++nt) {
      int n = w * 32 + nt * 16 + ln;
      f32x4 acc[2] = {z4, z4};
      #pragma unroll
      for (int kc = 0; kc < 2; ++kc)
        #pragma unroll
        for (int mt = 0; mt < 2; ++mt)
          acc[mt] = __builtin_amdgcn_mfma_f32_16x16x32_bf16(axf[mt][kc], w1pf[nt][kc], acc[mt], 0, 0, 0);
      #pragma unroll
      for (int mt = 0; mt < 2; ++mt)
        #pragma unroll
        for (int r = 0; r < 4; ++r) {
          int row = mt * 16 + lq * 4 + r;
          float v = fmaxf(acc[mt][r] + bias1p[nt], 0.f);
          G[(row * 512 + ((n << 1) ^ ((row & 7) << 4))) >> 1] = f2bf(v);
        }
    }
    __syncthreads();  // bar1: G ready (also orders prev P3 G2 reads)

    // P2: L1a = [F2 frags (kc<4) | G (kc>=4)] x [LDS (kc<6) | regs] -> G2
    {
      f32x4 acc1a[2] = {z4, z4};
      #pragma unroll
      for (int kc = 0; kc < 12; ++kc) {
        bf16x8 bfr = (kc < 6)
          ? *(const bf16x8*)(smem + (((w * 6 + kc) * 64 + lane) << 4))
          : wa_hi[kc - 6];
        #pragma unroll
        for (int mt = 0; mt < 2; ++mt) {
          bf16x8 afr;
          if (kc < 4) {
            afr = ff[mt * 4 + kc];
          } else {
            int kk = kc - 4;
            int row = mt * 16 + ln;
            afr = *(const bf16x8*)&G[(row * 512 + (((kk * 32 + kcol) << 1) ^ ((row & 7) << 4))) >> 1];
          }
          acc1a[mt] = __builtin_amdgcn_mfma_f32_16x16x32_bf16(afr, bfr, acc1a[mt], 0, 0, 0);
        }
      }
      int n = w * 16 + ln;
      #pragma unroll
      for (int mt = 0; mt < 2; ++mt)
        #pragma unroll
        for (int r = 0; r < 4; ++r) {
          int row = mt * 16 + lq * 4 + r;
          float v = fmaxf(acc1a[mt][r] + bias1a, 0.f);
          G2[(row * 256 + ((n << 1) ^ ((row & 7) << 4))) >> 1] = f2bf(v);
        }
    }
    __syncthreads();  // bar2: G2 ready; G reads done

    // P3 (waves 0..3): L1o: G2 @ wo -> out, fp32 scatter
    if (w < 4) {
      int mt = w & 1;
      int n  = (w >> 1) * 16 + ln;
      f32x4 acc = z4;
      #pragma unroll
      for (int kc = 0; kc < 4; ++kc) {
        int row = mt * 16 + ln;
        bf16x8 afr = *(const bf16x8*)&G2[(row * 256 + (((kc * 32 + kcol) << 1) ^ ((row & 7) << 4))) >> 1];
        acc = __builtin_amdgcn_mfma_f32_16x16x32_bf16(afr, wo[kc], acc, 0, 0, 0);
      }
      #pragma unroll
      for (int r = 0; r < 4; ++r) {
        int row = mt * 16 + lq * 4 + r;
        if (row < nr) {
          int rg = rl[row];
          out[(size_t)rg * 32 + n] = acc[r] + bias1o;
        }
      }
    }
  }
}

extern "C" void kernel_launch(void* const* d_in, const int* in_sizes, int n_in,
                              void* d_out, int out_size, void* d_ws, size_t ws_size,
                              hipStream_t stream) {
  const float* inp = (const float*)d_in[0];
  const float* w00 = (const float*)d_in[1];
  const float* b00 = (const float*)d_in[2];
  const float* w01 = (const float*)d_in[3];
  const float* b01 = (const float*)d_in[4];
  const float* w1p = (const float*)d_in[5];
  const float* b1p = (const float*)d_in[6];
  const float* w1a = (const float*)d_in[7];
  const float* b1a = (const float*)d_in[8];
  const float* w1o = (const float*)d_in[9];
  const float* b1o = (const float*)d_in[10];
  char*  ws  = (char*)d_ws;
  float* out = (float*)d_out;

  k_combo<<<368, 256, 0, stream>>>(w00, w01, w1p, w1a, w1o, inp, ws);
  k_part<<<NBLK, 256, 0, stream>>>((const int*)(ws + WS_BH),
                                   (const int*)(ws + WS_PAIR),
                                   (int*)(ws + WS_CNT), (int*)(ws + WS_BASE),
                                   (int*)(ws + WS_ROWLIST));
  k_fwdA<<<512, 512, 0, stream>>>(inp, b00, b01, ws);
  k_fwdB<<<512, 512, 0, stream>>>(inp, b1p, b1a, b1o, ws, out);
}

// Round 13
// 64.085 us; speedup vs baseline: 1.0481x; 1.0481x over previous
//
#include <hip/hip_runtime.h>
#include <hip/hip_bf16.h>

#define BATCH 32768
#define NPAIR 64
#define NBLK  128

typedef __bf16 bf16x8 __attribute__((ext_vector_type(8)));
typedef float  f32x4  __attribute__((ext_vector_type(4)));
static_assert(sizeof(bf16x8) == 16, "bf16x8 must be 16B");

// ---- workspace byte offsets ----
#define WS_CNT      0
#define WS_BASE     256
#define WS_BH       1024
#define WS_PAIR     66560
#define WS_ROWLIST  197632
#define WS_WF00     336896     /* frag-major [m][NT16][KC2][64]x16B = 32KB/m */
#define WS_WF01     599040     /* [m][NT8][KC8][64] = 64KB/m */
#define WS_WF1P     1123328    /* 32KB/m */
#define WS_WF1A     1385472    /* [m][NT8][KC12][64] = 96KB/m */
#define WS_WF1O     2171904    /* [m][NT2][KC4][64] = 8KB/m */
#define WS_F2       2237440    /* frag-major [pos16<=2176][kcb4][64]x16B = 8.9MB */

__device__ __forceinline__ unsigned short f2bf(float x) {
  __bf16 h = (__bf16)x;
  return __builtin_bit_cast(unsigned short, h);
}

#define KEEP(x) asm volatile("" : "+v"(x))
#define PIN8(A) asm volatile("" :: \
  "v"((A)[0]),"v"((A)[1]),"v"((A)[2]),"v"((A)[3]), \
  "v"((A)[4]),"v"((A)[5]),"v"((A)[6]),"v"((A)[7]))

// Blocks 0..239: weight fp32 -> bf16 MFMA-fragment-major. Blocks 240..367: route.
__global__ __launch_bounds__(256) void k_combo(const float* __restrict__ w00,
                                               const float* __restrict__ w01,
                                               const float* __restrict__ w1p,
                                               const float* __restrict__ w1a,
                                               const float* __restrict__ w1o,
                                               const float* __restrict__ inp,
                                               char* __restrict__ ws) {
  __shared__ unsigned short lds[64 * 72];
  int bid = blockIdx.x;
  if (bid >= 240) {
    int* h = (int*)lds;
    int rbid = bid - 240;
    int t = threadIdx.x;
    if (t < NPAIR) h[t] = 0;
    __syncthreads();
    int r = rbid * 256 + t;
    const float* q = inp + (size_t)r * 144 + 128;
    float4 u0 = *(const float4*)(q + 0);
    float4 u1 = *(const float4*)(q + 4);
    float4 v0 = *(const float4*)(q + 8);
    float4 v1 = *(const float4*)(q + 12);
    int a0 = 0;
    if (u0.y > 0.5f) a0 = 1; if (u0.z > 0.5f) a0 = 2; if (u0.w > 0.5f) a0 = 3;
    if (u1.x > 0.5f) a0 = 4; if (u1.y > 0.5f) a0 = 5; if (u1.z > 0.5f) a0 = 6; if (u1.w > 0.5f) a0 = 7;
    int a1 = 0;
    if (v0.y > 0.5f) a1 = 1; if (v0.z > 0.5f) a1 = 2; if (v0.w > 0.5f) a1 = 3;
    if (v1.x > 0.5f) a1 = 4; if (v1.y > 0.5f) a1 = 5; if (v1.z > 0.5f) a1 = 6; if (v1.w > 0.5f) a1 = 7;
    int p = a0 * 8 + a1;
    ((int*)(ws + WS_PAIR))[r] = p;
    atomicAdd(&h[p], 1);
    __syncthreads();
    if (t < NPAIR) ((int*)(ws + WS_BH))[rbid * NPAIR + t] = h[t];
    return;
  }
  const float* src; char* dst; int I, O, lt, NT, KC;
  if (bid < 32)       { src = w00; dst = ws + WS_WF00; I = 64;  O = 256; lt = bid;       NT = 16; KC = 2; }
  else if (bid < 96)  { src = w01; dst = ws + WS_WF01; I = 256; O = 128; lt = bid - 32;  NT = 8;  KC = 8; }
  else if (bid < 128) { src = w1p; dst = ws + WS_WF1P; I = 64;  O = 256; lt = bid - 96;  NT = 16; KC = 2; }
  else if (bid < 224) { src = w1a; dst = ws + WS_WF1A; I = 384; O = 128; lt = bid - 128; NT = 8;  KC = 12; }
  else                { src = w1o; dst = ws + WS_WF1O; I = 128; O = 32;  lt = bid - 224; NT = 2;  KC = 4; }
  int tI = I >> 6;
  int tO = (O + 63) >> 6;
  int m   = lt / (tI * tO);
  int rem = lt % (tI * tO);
  int ib = rem / tO, ob = rem % tO;
  int tx = threadIdx.x & 63, ty = threadIdx.x >> 6;
  const float* s = src + (size_t)m * I * O;
  #pragma unroll 4
  for (int s4 = 0; s4 < 16; ++s4) {
    int li = s4 * 4 + ty;
    int o  = ob * 64 + tx;
    float v = (o < O) ? s[(size_t)(ib * 64 + li) * O + o] : 0.f;
    lds[li * 72 + tx] = f2bf(v);
  }
  __syncthreads();
  int lane = threadIdx.x & 63, u = threadIdx.x >> 6;
  int ln = lane & 15, lq = lane >> 4;
  #pragma unroll
  for (int it = 0; it < 2; ++it) {
    int fi  = it * 4 + u;
    int ntl = fi >> 1, kcl = fi & 1;
    int ntg = ob * 4 + ntl, kcg = ib * 2 + kcl;
    if (ntg * 16 < O) {
      bf16x8 f;
      #pragma unroll
      for (int j = 0; j < 8; ++j)
        f[j] = __builtin_bit_cast(__bf16, lds[(kcl * 32 + lq * 8 + j) * 72 + ntl * 16 + ln]);
      *(bf16x8*)(dst + (((size_t)(m * NT + ntg) * KC + kcg) * 64 + lane) * 16) = f;
    }
  }
}

// k_part: scan (redundant per block, from bh in LDS) + scatter in ONE kernel.
__global__ __launch_bounds__(256) void k_part(const int* __restrict__ bh,
                                              const int* __restrict__ pairArr,
                                              int* __restrict__ cnt,
                                              int* __restrict__ base,
                                              int* __restrict__ rowlist) {
  __shared__ int lbh[NBLK * NPAIR];
  __shared__ int loff[NPAIR];
  __shared__ int h[NPAIR];
  int tid = threadIdx.x, bid = blockIdx.x;
  const int4* s4 = (const int4*)bh;
  int4* d4 = (int4*)lbh;
  #pragma unroll
  for (int i = 0; i < 8; ++i) d4[tid + i * 256] = s4[tid + i * 256];
  if (tid < NPAIR) h[tid] = 0;
  __syncthreads();
  if (tid < NPAIR) {
    int c = 0, partial = 0;
    for (int b = 0; b < NBLK; ++b) {
      int v = lbh[b * NPAIR + tid];
      if (b < bid) partial += v;
      c += v;
    }
    int ntp = (c + 31) >> 5;
    int z = ntp;
    #pragma unroll
    for (int d = 1; d < 64; d <<= 1) { int y = __shfl_up(z, d); if (tid >= d) z += y; }
    int pbase = (z - ntp) * 32;
    loff[tid] = pbase + partial;
    if (bid == 0) { cnt[tid] = c; base[tid] = pbase; }
  }
  __syncthreads();
  int r = bid * 256 + tid;
  int p = pairArr[r];
  int rank = atomicAdd(&h[p], 1);
  rowlist[loff[p] + rank] = r;
}

// XCD-affinity decode (both fwd kernels): bid = ((p>>3)*8+slice)*8 + (p&7),
// so bid%8 (presumed XCD) == p&7. F2 for pair p is written (fwdA) and read
// (fwdB) on the SAME XCD's L2; fwdB touches exactly one e1 weight set.
__device__ __forceinline__ void decode_ps(int bid, int& p, int& slice) {
  int hi = bid >> 3;
  p = ((hi >> 3) << 3) | (bid & 7);
  slice = hi & 7;
}

// Kernel A: e0-branch. LDS 64K -> 2 blocks/CU: WF01 kc<4 32K @0, H1 16K @32768,
// FS 8K @49152, xs 8K @57344. Coop input staging; frag-major F2 store.
__global__ __launch_bounds__(512, 4) void k_fwdA(
    const float* __restrict__ inp,
    const float* __restrict__ b00, const float* __restrict__ b01,
    char* __restrict__ ws)
{
  __shared__ char smem[65536];
  unsigned short* H1m = (unsigned short*)(smem + 32768);
  unsigned short* FS  = (unsigned short*)(smem + 49152);
  unsigned short* xs  = (unsigned short*)(smem + 57344);   // 32x64 bf16, swizzled

  int p, slice;
  decode_ps(blockIdx.x, p, slice);
  int e0 = p >> 3;
  int cnt = ((const int*)(ws + WS_CNT))[p];
  int pbase = ((const int*)(ws + WS_BASE))[p];
  int ntp = (cnt + 31) >> 5;
  if (slice >= ntp) return;
  const int* rlbase = (const int*)(ws + WS_ROWLIST) + pbase;
  char* f2 = ws + WS_F2;

  int tid = threadIdx.x;
  // stage WF01 kc<4 (32KB): LDS frag index (w2*4+kc) <- global frag (w2*8+kc)
  {
    const float4* s1 = (const float4*)(ws + WS_WF01 + (size_t)e0 * 65536);
    float4* d1 = (float4*)smem;
    #pragma unroll
    for (int i = 0; i < 4; ++i) {
      int fidx = tid + i * 512;               // 0..2047
      int chunk = fidx >> 6, within = fidx & 63;
      int w2 = chunk >> 2, kc = chunk & 3;
      d1[fidx] = s1[(w2 * 8 + kc) * 64 + within];
    }
  }

  int lane = tid & 63;
  int w    = tid >> 6;
  int ln = lane & 15, lq = lane >> 4;

  bf16x8 w00f[2][2], wcr[4];
  #pragma unroll
  for (int nt = 0; nt < 2; ++nt)
    #pragma unroll
    for (int kc = 0; kc < 2; ++kc)
      w00f[nt][kc] = *(const bf16x8*)(ws + WS_WF00 + (size_t)e0 * 32768 +
                                      ((((w * 2 + nt) * 2 + kc) * 64 + lane) << 4));
  #pragma unroll
  for (int kc = 0; kc < 4; ++kc)
    wcr[kc] = *(const bf16x8*)(ws + WS_WF01 + (size_t)e0 * 65536 +
                               (((w * 8 + 4 + kc) * 64 + lane) << 4));
  #pragma unroll
  for (int nt = 0; nt < 2; ++nt)
    #pragma unroll
    for (int kc = 0; kc < 2; ++kc) KEEP(w00f[nt][kc]);
  #pragma unroll
  for (int kc = 0; kc < 4; ++kc) KEEP(wcr[kc]);

  float bias00[2];
  #pragma unroll
  for (int nt = 0; nt < 2; ++nt) bias00[nt] = b00[e0 * 256 + w * 32 + nt * 16 + ln];
  float bias01 = b01[e0 * 128 + w * 16 + ln];

  const f32x4 z4 = {0.f, 0.f, 0.f, 0.f};
  int srow = tid >> 4, scol = tid & 15;     // staging: row 0..31, float4 0..15
  __syncthreads();  // weights staged

  for (int t = slice; t < ntp; t += 8) {
    int nr = min(32, cnt - t * 32);
    int rb = pbase + t * 32;
    const int* rl = rlbase + t * 32;

    // coop stage: one coalesced float4 per thread -> bf16 8B into swizzled xs
    {
      int rg = (srow < nr) ? rl[srow] : -1;
      ushort4 v8 = {0, 0, 0, 0};
      if (rg >= 0) {
        float4 u = *(const float4*)(inp + (size_t)rg * 144 + scol * 4);
        v8.x = f2bf(u.x); v8.y = f2bf(u.y); v8.z = f2bf(u.z); v8.w = f2bf(u.w);
      }
      int byte = (srow * 128 + scol * 8) ^ ((srow & 7) << 4);
      *(ushort4*)((char*)xs + byte) = v8;
    }
    __syncthreads();  // barA: xs ready; FS reads (prev F2 store) done

    // P1: L00 (reg weights, xs frags) -> H1 (swizzled)
    bf16x8 axf[2][2];
    #pragma unroll
    for (int mt = 0; mt < 2; ++mt)
      #pragma unroll
      for (int kc = 0; kc < 2; ++kc) {
        int row = mt * 16 + ln;
        int byte = (row * 128 + kc * 64 + lq * 16) ^ ((row & 7) << 4);
        axf[mt][kc] = *(const bf16x8*)((const char*)xs + byte);
      }
    #pragma unroll
    for (int nt = 0; nt < 2; ++nt) {
      int n = w * 32 + nt * 16 + ln;
      f32x4 acc[2] = {z4, z4};
      #pragma unroll
      for (int kc = 0; kc < 2; ++kc)
        #pragma unroll
        for (int mt = 0; mt < 2; ++mt)
          acc[mt] = __builtin_amdgcn_mfma_f32_16x16x32_bf16(axf[mt][kc], w00f[nt][kc], acc[mt], 0, 0, 0);
      #pragma unroll
      for (int mt = 0; mt < 2; ++mt)
        #pragma unroll
        for (int r = 0; r < 4; ++r) {
          int row = mt * 16 + lq * 4 + r;
          float v = fmaxf(acc[mt][r] + bias00[nt], 0.f);
          H1m[(row * 512 + ((n << 1) ^ ((row & 7) << 4))) >> 1] = f2bf(v);
        }
    }
    __syncthreads();  // barB: H1 ready

    // P2: L01 (LDS kc<4 + reg kc>=4) -> acc; FS write
    {
      f32x4 acc[2] = {z4, z4};
      int kcol = lq * 8;
      #pragma unroll
      for (int kc = 0; kc < 8; ++kc) {
        bf16x8 bfr = (kc < 4)
          ? *(const bf16x8*)(smem + (((w * 4 + kc) * 64 + lane) << 4))
          : wcr[kc - 4];
        #pragma unroll
        for (int mt = 0; mt < 2; ++mt) {
          int row = mt * 16 + ln;
          bf16x8 afr = *(const bf16x8*)&H1m[(row * 512 + (((kc * 32 + kcol) << 1) ^ ((row & 7) << 4))) >> 1];
          acc[mt] = __builtin_amdgcn_mfma_f32_16x16x32_bf16(afr, bfr, acc[mt], 0, 0, 0);
        }
      }
      int c = w * 16 + ln;
      #pragma unroll
      for (int mt = 0; mt < 2; ++mt)
        #pragma unroll
        for (int r = 0; r < 4; ++r) {
          int row = mt * 16 + lq * 4 + r;
          float v = fmaxf(acc[mt][r] + bias01, 0.f);
          FS[(row * 256 + ((c << 1) ^ ((row & 7) << 4))) >> 1] = f2bf(v);
        }
    }
    __syncthreads();  // barC: FS ready

    // frag-major F2 store: wave w -> frag (mt=w>>2, kcb=w&3); 1024B contiguous
    {
      int mt = w >> 2, kcb = w & 3;
      int row = mt * 16 + ln;
      int koff = kcb * 32 + lq * 8;
      bf16x8 v = *(const bf16x8*)&FS[(row * 256 + ((koff << 1) ^ ((row & 7) << 4))) >> 1];
      *(bf16x8*)(f2 + ((size_t)(((rb >> 4) + mt) * 4 + kcb)) * 1024 + lane * 16) = v;
    }
  }
}

// Kernel B: e1-branch. LDS 80K -> 2 blocks/CU: WF1A kc<6 48K @0, G 16K @49152,
// G2 8K @65536, xs 8K @73728. Coop input staging; F2 frag prefetch (PIN8).
__global__ __launch_bounds__(512, 4) void k_fwdB(
    const float* __restrict__ inp,
    const float* __restrict__ b1p, const float* __restrict__ b1a,
    const float* __restrict__ b1o,
    char* __restrict__ ws, float* __restrict__ out)
{
  __shared__ char smem[81920];
  unsigned short* G  = (unsigned short*)(smem + 49152);
  unsigned short* G2 = (unsigned short*)(smem + 65536);
  unsigned short* xs = (unsigned short*)(smem + 73728);   // 32x64 bf16, swizzled

  int p, slice;
  decode_ps(blockIdx.x, p, slice);
  int e1 = p & 7;
  int cnt = ((const int*)(ws + WS_CNT))[p];
  int pbase = ((const int*)(ws + WS_BASE))[p];
  int ntp = (cnt + 31) >> 5;
  if (slice >= ntp) return;
  const int* rlbase = (const int*)(ws + WS_ROWLIST) + pbase;
  const char* f2 = ws + WS_F2;

  int tid = threadIdx.x;
  // stage WF1A kc<6 (48KB)
  {
    const float4* s1 = (const float4*)(ws + WS_WF1A + (size_t)e1 * 98304);
    float4* d1 = (float4*)smem;
    #pragma unroll
    for (int i = 0; i < 6; ++i) {
      int fidx = tid + i * 512;
      int chunk = fidx >> 6, within = fidx & 63;
      int w2 = chunk / 6, kc = chunk % 6;
      d1[fidx] = s1[(w2 * 12 + kc) * 64 + within];
    }
  }

  int lane = tid & 63;
  int w    = tid >> 6;
  int ln = lane & 15, lq = lane >> 4;
  int kcol = lq * 8;

  bf16x8 w1pf[2][2];
  #pragma unroll
  for (int nt = 0; nt < 2; ++nt)
    #pragma unroll
    for (int kc = 0; kc < 2; ++kc)
      w1pf[nt][kc] = *(const bf16x8*)(ws + WS_WF1P + (size_t)e1 * 32768 +
                                      ((((w * 2 + nt) * 2 + kc) * 64 + lane) << 4));
  bf16x8 wa_hi[6];
  #pragma unroll
  for (int j = 0; j < 6; ++j)
    wa_hi[j] = *(const bf16x8*)(ws + WS_WF1A + (size_t)e1 * 98304 +
                                (((w * 12 + 6 + j) * 64 + lane) << 4));
  #pragma unroll
  for (int nt = 0; nt < 2; ++nt)
    #pragma unroll
    for (int kc = 0; kc < 2; ++kc) KEEP(w1pf[nt][kc]);
  #pragma unroll
  for (int j = 0; j < 6; ++j) KEEP(wa_hi[j]);

  float bias1p[2];
  #pragma unroll
  for (int nt = 0; nt < 2; ++nt) bias1p[nt] = b1p[e1 * 256 + w * 32 + nt * 16 + ln];
  float bias1a = b1a[e1 * 128 + w * 16 + ln];
  float bias1o = (w < 4) ? b1o[e1 * 32 + (w >> 1) * 16 + ln] : 0.f;

  const f32x4 z4 = {0.f, 0.f, 0.f, 0.f};
  int srow = tid >> 4, scol = tid & 15;
  __syncthreads();  // weights staged

  for (int t = slice; t < ntp; t += 8) {
    int nr = min(32, cnt - t * 32);
    int rb = pbase + t * 32;
    const int* rl = rlbase + t * 32;

    // coop stage feat1 + F2 frag prefetch (batched, overlap barA)
    {
      int rg = (srow < nr) ? rl[srow] : -1;
      ushort4 v8 = {0, 0, 0, 0};
      if (rg >= 0) {
        float4 u = *(const float4*)(inp + (size_t)rg * 144 + 64 + scol * 4);
        v8.x = f2bf(u.x); v8.y = f2bf(u.y); v8.z = f2bf(u.z); v8.w = f2bf(u.w);
      }
      int byte = (srow * 128 + scol * 8) ^ ((srow & 7) << 4);
      *(ushort4*)((char*)xs + byte) = v8;
    }
    bf16x8 ff[8];
    #pragma unroll
    for (int mt = 0; mt < 2; ++mt) {
      size_t pb = (size_t)(((rb >> 4) + mt) * 4) * 1024;
      #pragma unroll
      for (int kcb = 0; kcb < 4; ++kcb)
        ff[mt * 4 + kcb] = *(const bf16x8*)(f2 + pb + kcb * 1024 + lane * 16);
    }
    PIN8(ff);
    __syncthreads();  // barA: xs ready; prev-tile G2 reads done

    // P1: L1p (reg weights, xs frags) -> G (swizzled)
    bf16x8 axf[2][2];
    #pragma unroll
    for (int mt = 0; mt < 2; ++mt)
      #pragma unroll
      for (int kc = 0; kc < 2; ++kc) {
        int row = mt * 16 + ln;
        int byte = (row * 128 + kc * 64 + lq * 16) ^ ((row & 7) << 4);
        axf[mt][kc] = *(const bf16x8*)((const char*)xs + byte);
      }
    #pragma unroll
    for (int nt = 0; nt < 2; ++nt) {
      int n = w * 32 + nt * 16 + ln;
      f32x4 acc[2] = {z4, z4};
      #pragma unroll
      for (int kc = 0; kc < 2; ++kc)
        #pragma unroll
        for (int mt = 0; mt < 2; ++mt)
          acc[mt] = __builtin_amdgcn_mfma_f32_16x16x32_bf16(axf[mt][kc], w1pf[nt][kc], acc[mt], 0, 0, 0);
      #pragma unroll
      for (int mt = 0; mt < 2; ++mt)
        #pragma unroll
        for (int r = 0; r < 4; ++r) {
          int row = mt * 16 + lq * 4 + r;
          float v = fmaxf(acc[mt][r] + bias1p[nt], 0.f);
          G[(row * 512 + ((n << 1) ^ ((row & 7) << 4))) >> 1] = f2bf(v);
        }
    }
    __syncthreads();  // barB: G ready; prev-tile G2 reads long done

    // P2: L1a = [ff (kc<4) | G (kc>=4)] x [LDS (kc<6) | regs (kc>=6)] -> G2
    {
      f32x4 acc1a[2] = {z4, z4};
      #pragma unroll
      for (int kc = 0; kc < 12; ++kc) {
        bf16x8 bfr = (kc < 6)
          ? *(const bf16x8*)(smem + (((w * 6 + kc) * 64 + lane) << 4))
          : wa_hi[kc - 6];
        #pragma unroll
        for (int mt = 0; mt < 2; ++mt) {
          bf16x8 afr;
          if (kc < 4) {
            afr = ff[mt * 4 + kc];
          } else {
            int kk = kc - 4;
            int row = mt * 16 + ln;
            afr = *(const bf16x8*)&G[(row * 512 + (((kk * 32 + kcol) << 1) ^ ((row & 7) << 4))) >> 1];
          }
          acc1a[mt] = __builtin_amdgcn_mfma_f32_16x16x32_bf16(afr, bfr, acc1a[mt], 0, 0, 0);
        }
      }
      int n = w * 16 + ln;
      #pragma unroll
      for (int mt = 0; mt < 2; ++mt)
        #pragma unroll
        for (int r = 0; r < 4; ++r) {
          int row = mt * 16 + lq * 4 + r;
          float v = fmaxf(acc1a[mt][r] + bias1a, 0.f);
          G2[(row * 256 + ((n << 1) ^ ((row & 7) << 4))) >> 1] = f2bf(v);
        }
    }
    __syncthreads();  // barC: G2 ready

    // P3 (waves 0..3): L1o: G2 @ W1o (batched per-tile loads) -> out
    if (w < 4) {
      int mt = w & 1;
      int n  = (w >> 1) * 16 + ln;
      bf16x8 wo[4];
      #pragma unroll
      for (int kc = 0; kc < 4; ++kc)
        wo[kc] = *(const bf16x8*)(ws + WS_WF1O + (size_t)e1 * 8192 +
                                  ((((w >> 1) * 4 + kc) * 64 + lane) << 4));
      f32x4 acc = z4;
      #pragma unroll
      for (int kc = 0; kc < 4; ++kc) {
        int row = mt * 16 + ln;
        bf16x8 afr = *(const bf16x8*)&G2[(row * 256 + (((kc * 32 + kcol) << 1) ^ ((row & 7) << 4))) >> 1];
        acc = __builtin_amdgcn_mfma_f32_16x16x32_bf16(afr, wo[kc], acc, 0, 0, 0);
      }
      #pragma unroll
      for (int r = 0; r < 4; ++r) {
        int row = mt * 16 + lq * 4 + r;
        if (row < nr) {
          int rg = rl[row];
          out[(size_t)rg * 32 + n] = acc[r] + bias1o;
        }
      }
    }
  }
}

extern "C" void kernel_launch(void* const* d_in, const int* in_sizes, int n_in,
                              void* d_out, int out_size, void* d_ws, size_t ws_size,
                              hipStream_t stream) {
  const float* inp = (const float*)d_in[0];
  const float* w00 = (const float*)d_in[1];
  const float* b00 = (const float*)d_in[2];
  const float* w01 = (const float*)d_in[3];
  const float* b01 = (const float*)d_in[4];
  const float* w1p = (const float*)d_in[5];
  const float* b1p = (const float*)d_in[6];
  const float* w1a = (const float*)d_in[7];
  const float* b1a = (const float*)d_in[8];
  const float* w1o = (const float*)d_in[9];
  const float* b1o = (const float*)d_in[10];
  char*  ws  = (char*)d_ws;
  float* out = (float*)d_out;

  k_combo<<<368, 256, 0, stream>>>(w00, w01, w1p, w1a, w1o, inp, ws);
  k_part<<<NBLK, 256, 0, stream>>>((const int*)(ws + WS_BH),
                                   (const int*)(ws + WS_PAIR),
                                   (int*)(ws + WS_CNT), (int*)(ws + WS_BASE),
                                   (int*)(ws + WS_ROWLIST));
  k_fwdA<<<512, 512, 0, stream>>>(inp, b00, b01, ws);
  k_fwdB<<<512, 512, 0, stream>>>(inp, b1p, b1a, b1o, ws, out);
}